// Round 4
// baseline (101.960 us; speedup 1.0000x reference)
//
#include <hip/hip_runtime.h>
#include <math.h>

#define BB 8
#define HH 16
#define NN 1024
#define TB 256
#define PACKF (BB * NN * 4)   // floats in the packed area (128 KB)

typedef float f32x16 __attribute__((ext_vector_type(16)));

// ws layout (floats):
//   [0, PACKF)            packed scan points {x, y, z, x^2+y^2+z^2} per (b, j)
//   [PACKF, PACKF + 512)  block sums: ws[PACKF + bh*4 + q]
// All written every iteration, plain stores, no atomics, no init needed.

// ---------------------------------------------------------------------------
// pack: one thread per point, writes float4{x,y,z,sq}. 128 KB total ->
// L2/K$-resident for the chamfer's scalar loads. sq expression identical to
// the rounds-0..3 staging (x*x + y*y + z*z).
// ---------------------------------------------------------------------------
__global__ __launch_bounds__(TB) void pack_kernel(
    const float* __restrict__ sp,
    float* __restrict__ ws)
{
    int idx = blockIdx.x * TB + threadIdx.x;       // 0 .. 8191
    float x = sp[idx * 3 + 0], y = sp[idx * 3 + 1], z = sp[idx * 3 + 2];
    ((float4*)ws)[idx] = make_float4(x, y, z, x * x + y * y + z * z);
}

// ---------------------------------------------------------------------------
// chamfer: ONLY pass A (reflection-isometry: both chamfer terms are equal).
// Block (bh, q): own = reflected points [q*256,+256) (1/thread, pre-scaled
// by -2); scan = ALL 1024 points so min_j completes in-block and the i-sum
// collapses to ONE float per block.
//
// ROUND-4 CHANGE: scan stream moved to the SCALAR pipe via inline-asm
// s_load_dwordx16. Rounds 0-2 were broadcast-issue-bound: 1024 broadcast
// ds_read_b128/wave x ~12 cyc on the per-CU LDS pipe ~= 41 us/CU vs 7.7 us
// of FMA work. Round 3 proved the compiler will NOT auto-promote uniform
// global loads to s_load (it emitted per-lane VMEM broadcasts instead).
// Here the packed {x,y,z,sq} stream is loaded 8-points-at-a-time with two
// s_load_dwordx16 + s_waitcnt lgkmcnt(0) INSIDE one asm block (outputs feed
// the FMAs -> dataflow-ordered, no rule-18 hoisting hazard). FMAs take the
// SGPR values directly as the single legal SGPR operand; the chain base
// fmaf(mz, s_z, s_sq) costs one v_mov per point. Hot loop per 8 points:
// 2 SMEM + 36 VALU, ZERO LDS, ZERO VMEM. Expression trees (sq at chain
// base, mz/my/mx nesting, paired min accumulators, osq added after the min)
// are bit-identical to the passing rounds.
// ---------------------------------------------------------------------------
__global__ __launch_bounds__(TB) void chamfer_kernel(
    const float* __restrict__ y_pred,
    const float* __restrict__ sp,
    float* __restrict__ ws)
{
    __shared__ float wsum[4];

    const int blk = blockIdx.x;          // 512 blocks
    const int bh  = blk >> 2;
    const int q   = blk & 3;
    const int b   = bh >> 4;             // HH = 16
    const int tid = threadIdx.x;

    float pnx = y_pred[bh * 4 + 0];
    float pny = y_pred[bh * 4 + 1];
    float pnz = y_pred[bh * 4 + 2];
    float pd  = y_pred[bh * 4 + 3];
    float inv = 1.0f / sqrtf(pnx * pnx + pny * pny + pnz * pnz);
    pnx *= inv; pny *= inv; pnz *= inv;

    const float* __restrict__ spb = sp + (size_t)b * NN * 3;

    // own point: reflected, pre-scaled by -2 (identical to rounds 2/3)
    float mx, my, mz, osq;
    {
        int i = q * TB + tid;
        float x = spb[i * 3 + 0], y = spb[i * 3 + 1], z = spb[i * 3 + 2];
        float proj = x * pnx + y * pny + z * pnz + pd;
        x -= 2.0f * proj * pnx;
        y -= 2.0f * proj * pny;
        z -= 2.0f * proj * pnz;
        osq = x * x + y * y + z * z;
        mx = -2.0f * x; my = -2.0f * y; mz = -2.0f * z;
    }

    float m0 = 3.4e38f, m1 = 3.4e38f;

    // packed scan stream for this batch (64B-aligned; offsets 0 and 64)
    const float* p = ws + (size_t)b * NN * 4;

#define DIST(X, Y, Z, W) fmaf(mx, X, fmaf(my, Y, fmaf(mz, Z, W)))
    for (int j = 0; j < NN; j += 8, p += 32) {
        f32x16 A, B;
        asm volatile(
            "s_load_dwordx16 %0, %2, 0\n\t"
            "s_load_dwordx16 %1, %2, 64\n\t"
            "s_waitcnt lgkmcnt(0)"
            : "=&s"(A), "=&s"(B)
            : "s"(p));
        float d0 = DIST(A[0],  A[1],  A[2],  A[3]);
        float d1 = DIST(A[4],  A[5],  A[6],  A[7]);
        float d2 = DIST(A[8],  A[9],  A[10], A[11]);
        float d3 = DIST(A[12], A[13], A[14], A[15]);
        float d4 = DIST(B[0],  B[1],  B[2],  B[3]);
        float d5 = DIST(B[4],  B[5],  B[6],  B[7]);
        float d6 = DIST(B[8],  B[9],  B[10], B[11]);
        float d7 = DIST(B[12], B[13], B[14], B[15]);
        // same accumulator pairing as rounds 2/3 (min3-friendly)
        m0 = fminf(fminf(m0, d0), d1);
        m1 = fminf(fminf(m1, d2), d3);
        m0 = fminf(fminf(m0, d4), d5);
        m1 = fminf(fminf(m1, d6), d7);
    }
#undef DIST

    float dmin = osq + fminf(m0, m1);      // complete min_j d2 for own i

    // in-block sum over 256 own points (deterministic, same as rounds 2/3)
    float s = dmin;
    for (int off = 32; off; off >>= 1) s += __shfl_down(s, off, 64);
    if ((tid & 63) == 0) wsum[tid >> 6] = s;
    __syncthreads();
    if (tid == 0)
        ws[PACKF + bh * 4 + q] = (wsum[0] + wsum[1]) + (wsum[2] + wsum[3]);
}

// ---------------------------------------------------------------------------
// finalize (per batch, 256 threads): centroid; sde[h] = 2/N * (4 block sums
// in fixed order); conf; angle-NMS; stable rank; write. Verbatim round 2/3
// except the sums base offset.
// ---------------------------------------------------------------------------
__global__ __launch_bounds__(TB) void finalize_kernel(
    const float* __restrict__ ws,
    const float* __restrict__ y_pred,
    const float* __restrict__ sp,
    float* __restrict__ out)
{
    const int b   = blockIdx.x;
    const int tid = threadIdx.x;

    __shared__ float sde_s[HH], nx_s[HH], ny_s[HH], nz_s[HH], d_s[HH], conf_s[HH];
    __shared__ float cmacc[3];
    __shared__ int keep_s[HH];

    if (tid < 3) cmacc[tid] = 0.0f;
    __syncthreads();

    // centroid: 1024 samples over 256 threads
    const float* spb = sp + (size_t)b * NN * 3;
    float sx = 0.0f, sy = 0.0f, sz = 0.0f;
    for (int p = tid; p < NN; p += TB) {
        sx += spb[p * 3 + 0];
        sy += spb[p * 3 + 1];
        sz += spb[p * 3 + 2];
    }
    for (int off = 32; off; off >>= 1) {
        sx += __shfl_down(sx, off, 64);
        sy += __shfl_down(sy, off, 64);
        sz += __shfl_down(sz, off, 64);
    }
    if ((tid & 63) == 0) {
        atomicAdd(&cmacc[0], sx);
        atomicAdd(&cmacc[1], sy);
        atomicAdd(&cmacc[2], sz);
    }
    __syncthreads();

    const float cmx = cmacc[0] / NN, cmy = cmacc[1] / NN, cmz = cmacc[2] / NN;

    if (tid < HH) {
        int h = tid;
        float nx = y_pred[(b * HH + h) * 4 + 0];
        float ny = y_pred[(b * HH + h) * 4 + 1];
        float nz = y_pred[(b * HH + h) * 4 + 2];
        float d  = y_pred[(b * HH + h) * 4 + 3];
        float inv = 1.0f / sqrtf(nx * nx + ny * ny + nz * nz);
        nx *= inv; ny *= inv; nz *= inv;
        nx_s[h] = nx; ny_s[h] = ny; nz_s[h] = nz; d_s[h] = d;
        const float* w = ws + PACKF + (size_t)(b * HH + h) * 4;
        // fixed-order sum of the 4 block partials, both chamfer terms equal
        sde_s[h] = ((w[0] + w[1]) + (w[2] + w[3])) * (2.0f / NN);
    }
    __syncthreads();

    if (tid < HH) {
        int h = tid;
        float mn = sde_s[0], mx = sde_s[0];
        for (int g = 1; g < HH; ++g) {
            mn = fminf(mn, sde_s[g]);
            mx = fmaxf(mx, sde_s[g]);
        }
        float sde  = sde_s[h];
        float conf = 1.0f - (sde - mn) / fabsf(mx - mn);
        conf_s[h]  = conf;
        bool valid = (sde <= 10.0f);
        bool sup   = false;
        if (valid) {
            for (int g = 0; g < HH; ++g) {
                if (g == h) continue;
                float c = nx_s[h] * nx_s[g] + ny_s[h] * ny_s[g] + nz_s[h] * nz_s[g];
                c = fminf(1.0f, fmaxf(-1.0f, c));
                float ang = acosf(c) * 57.29577951308232f;
                bool close = (ang < 30.0f) || (180.0f - ang < 30.0f);
                if (close && (sde_s[g] <= 10.0f) && (sde >= sde_s[g])) sup = true;
            }
        }
        keep_s[h] = (valid && !sup) ? 1 : 0;
    }
    __syncthreads();

    if (tid < HH) {
        int h = tid;
        // stable descending rank on key = keep ? conf : -inf (jnp.argsort(-key))
        float keyh = keep_s[h] ? conf_s[h] : -INFINITY;
        int pos = 0;
        for (int g = 0; g < HH; ++g) {
            float keyg = keep_s[g] ? conf_s[g] : -INFINITY;
            if (keyg > keyh || (keyg == keyh && g < h)) ++pos;
        }
        float nx = nx_s[h], ny = ny_s[h], nz = nz_s[h];
        float t  = nx * cmx + ny * cmy + nz * cmz + d_s[h];
        float px = cmx - t * nx, py = cmy - t * ny, pz = cmz - t * nz;

        float* o = out + (size_t)(b * HH + pos) * 8;
        if (keep_s[h]) {
            o[0] = nx; o[1] = ny; o[2] = nz;
            o[3] = px; o[4] = py; o[5] = pz;
            o[6] = conf_s[h];
            o[7] = sde_s[h];
        } else {
            for (int c = 0; c < 8; ++c) o[c] = 0.0f;
        }
    }
}

extern "C" void kernel_launch(void* const* d_in, const int* in_sizes, int n_in,
                              void* d_out, int out_size, void* d_ws, size_t ws_size,
                              hipStream_t stream) {
    const float* y_pred = (const float*)d_in[0];   // (8,16,4) f32
    const float* sp     = (const float*)d_in[1];   // (8,1024,3) f32
    float* out          = (float*)d_out;           // (8,16,8) f32
    float* ws           = (float*)d_ws;            // 128 KB pack + 512 sums

    pack_kernel<<<dim3(BB * NN / TB), dim3(TB), 0, stream>>>(sp, ws);
    chamfer_kernel<<<dim3(BB * HH * 4), dim3(TB), 0, stream>>>(y_pred, sp, ws);
    finalize_kernel<<<dim3(BB), dim3(TB), 0, stream>>>(ws, y_pred, sp, out);
}

// Round 5
// 75.400 us; speedup vs baseline: 1.3523x; 1.3523x over previous
//
#include <hip/hip_runtime.h>
#include <math.h>

#define BB 8
#define HH 16
#define NN 1024
#define TB 256
#define NSC 4            // scan chunks per bh
#define SCH 256          // scan points per chunk (NN / NSC)
#define POWN 4           // own points per thread (block owns all 1024)
#define SUMBASE (BB * HH * NSC * NN)   // 524288 floats of partials, then sums

// ws layout (floats):
//   [0, SUMBASE)            part[(bh*NSC+sc)*NN + i] = osq_i + min over chunk
//                           sc of dot-term  (2 MB, coalesced writes)
//   [SUMBASE, SUMBASE+128)  per-bh sums from the reduce kernel
// Every slot written every iteration, plain stores, no atomics, no init.

// ---------------------------------------------------------------------------
// chamfer: ONLY pass A (reflection-isometry: both chamfer terms equal).
// ROUND-5: combine the proven-best pieces of rounds 0-4.
//  - Geometry from round 1 (best reads/pair): block (bh, sc); own = ALL 1024
//    reflected points (POWN=4/thread, pre-scaled by -2); scan = 256 pts in
//    LDS. Only 256 broadcast ds_read_b128 per wave serving 1024 pairs/thread
//    (0.25 reads/pair) -> VALU-bound, not LDS-issue-bound (rounds 0/2 paid
//    512-1024 reads/wave) and not SMEM-latency-bound (round 4's s_load loop
//    serialized 128 full latencies/wave: 41 us, VALUBusy 32%).
//  - Codegen from round 2: plain indexed LDS loads, NO register rotation
//    (round 1's 32 v_movs/group regression), compiler's counted lgkmcnt
//    pipelining. DIST/min3 expression trees bit-identical to passing rounds.
// ---------------------------------------------------------------------------
__global__ __launch_bounds__(TB) void chamfer_kernel(
    const float* __restrict__ y_pred,
    const float* __restrict__ sp,
    float* __restrict__ ws)
{
    __shared__ __align__(16) float4 pts[SCH];   // 4 KB

    const int blk = blockIdx.x;          // 512 blocks
    const int bh  = blk >> 2;
    const int sc  = blk & (NSC - 1);
    const int b   = bh >> 4;             // HH = 16
    const int tid = threadIdx.x;

    float pnx = y_pred[bh * 4 + 0];
    float pny = y_pred[bh * 4 + 1];
    float pnz = y_pred[bh * 4 + 2];
    float pd  = y_pred[bh * 4 + 3];
    float inv = 1.0f / sqrtf(pnx * pnx + pny * pny + pnz * pnz);
    pnx *= inv; pny *= inv; pnz *= inv;

    const float* __restrict__ spb = sp + (size_t)b * NN * 3;

    // stage scan chunk: raw samples with squared norm (1 point / thread)
    {
        int j = sc * SCH + tid;
        float x = spb[j * 3 + 0], y = spb[j * 3 + 1], z = spb[j * 3 + 2];
        pts[tid] = make_float4(x, y, z, x * x + y * y + z * z);
    }

    // own points: reflected, pre-scaled by -2 (identical math to rounds 2-4)
    float mx[POWN], my[POWN], mz[POWN], osq[POWN];
#pragma unroll
    for (int u = 0; u < POWN; ++u) {
        int i = u * TB + tid;
        float x = spb[i * 3 + 0], y = spb[i * 3 + 1], z = spb[i * 3 + 2];
        float proj = x * pnx + y * pny + z * pnz + pd;
        x -= 2.0f * proj * pnx;
        y -= 2.0f * proj * pny;
        z -= 2.0f * proj * pnz;
        osq[u] = x * x + y * y + z * z;
        mx[u] = -2.0f * x; my[u] = -2.0f * y; mz[u] = -2.0f * z;
    }
    __syncthreads();

    float m0[POWN], m1[POWN];
#pragma unroll
    for (int u = 0; u < POWN; ++u) { m0[u] = 3.4e38f; m1[u] = 3.4e38f; }

#define DIST(qq, u) fmaf(mx[u], qq.x, fmaf(my[u], qq.y, fmaf(mz[u], qq.z, qq.w)))
    for (int j = 0; j < SCH; j += 4) {
        float4 q0 = pts[j + 0];
        float4 q1 = pts[j + 1];
        float4 q2 = pts[j + 2];
        float4 q3 = pts[j + 3];
#pragma unroll
        for (int u = 0; u < POWN; ++u) {
            float d0 = DIST(q0, u);
            float d1 = DIST(q1, u);
            float d2 = DIST(q2, u);
            float d3 = DIST(q3, u);
            m0[u] = fminf(fminf(m0[u], d0), d1);   // v_min3_f32
            m1[u] = fminf(fminf(m1[u], d2), d3);
        }
    }
#undef DIST

    // per-own-point chunk partial (osq constant across chunks, so
    // min over chunks of (osq + partial) == osq + overall min)
    float* wp = ws + (size_t)(bh * NSC + sc) * NN;
#pragma unroll
    for (int u = 0; u < POWN; ++u)
        wp[u * TB + tid] = osq[u] + fminf(m0[u], m1[u]);
}

// ---------------------------------------------------------------------------
// reduce: 128 blocks (one per bh), 256 threads. Thread t reads float4 #t of
// each of the NSC chunk rows (perfectly coalesced: row = 256 float4 = 256
// lanes), min across chunks per component, sums its 4 components, then a
// deterministic block sum (shfl tree + fixed-order 4-wave combine) -> ONE
// float per bh. Spreads the 2 MB partial read over 128 CUs in parallel
// (rounds 0/1 did this on 8 blocks: 20-25 us; here ~2 us).
// ---------------------------------------------------------------------------
__global__ __launch_bounds__(TB) void reduce_kernel(
    const float* __restrict__ ws_in,
    float* __restrict__ ws_out)
{
    __shared__ float wsum[4];
    const int bh  = blockIdx.x;
    const int tid = threadIdx.x;

    const float4* r0 = (const float4*)(ws_in + (size_t)(bh * NSC + 0) * NN);
    const float4* r1 = (const float4*)(ws_in + (size_t)(bh * NSC + 1) * NN);
    const float4* r2 = (const float4*)(ws_in + (size_t)(bh * NSC + 2) * NN);
    const float4* r3 = (const float4*)(ws_in + (size_t)(bh * NSC + 3) * NN);

    float4 a0 = r0[tid], a1 = r1[tid], a2 = r2[tid], a3 = r3[tid];
    float e0 = fminf(fminf(a0.x, a1.x), fminf(a2.x, a3.x));
    float e1 = fminf(fminf(a0.y, a1.y), fminf(a2.y, a3.y));
    float e2 = fminf(fminf(a0.z, a1.z), fminf(a2.z, a3.z));
    float e3 = fminf(fminf(a0.w, a1.w), fminf(a2.w, a3.w));
    float s  = (e0 + e1) + (e2 + e3);

    for (int off = 32; off; off >>= 1) s += __shfl_down(s, off, 64);
    if ((tid & 63) == 0) wsum[tid >> 6] = s;
    __syncthreads();
    if (tid == 0)
        ws_out[SUMBASE + bh] = (wsum[0] + wsum[1]) + (wsum[2] + wsum[3]);
}

// ---------------------------------------------------------------------------
// finalize (per batch, 256 threads): centroid; sde[h] = 2/N * per-bh sum;
// conf; angle-NMS; stable rank; write. Heavy phase is now 16 floats/batch.
// ---------------------------------------------------------------------------
__global__ __launch_bounds__(TB) void finalize_kernel(
    const float* __restrict__ ws,
    const float* __restrict__ y_pred,
    const float* __restrict__ sp,
    float* __restrict__ out)
{
    const int b   = blockIdx.x;
    const int tid = threadIdx.x;

    __shared__ float sde_s[HH], nx_s[HH], ny_s[HH], nz_s[HH], d_s[HH], conf_s[HH];
    __shared__ float cmacc[3];
    __shared__ int keep_s[HH];

    if (tid < 3) cmacc[tid] = 0.0f;
    __syncthreads();

    // centroid: 1024 samples over 256 threads
    const float* spb = sp + (size_t)b * NN * 3;
    float sx = 0.0f, sy = 0.0f, sz = 0.0f;
    for (int p = tid; p < NN; p += TB) {
        sx += spb[p * 3 + 0];
        sy += spb[p * 3 + 1];
        sz += spb[p * 3 + 2];
    }
    for (int off = 32; off; off >>= 1) {
        sx += __shfl_down(sx, off, 64);
        sy += __shfl_down(sy, off, 64);
        sz += __shfl_down(sz, off, 64);
    }
    if ((tid & 63) == 0) {
        atomicAdd(&cmacc[0], sx);
        atomicAdd(&cmacc[1], sy);
        atomicAdd(&cmacc[2], sz);
    }
    __syncthreads();

    const float cmx = cmacc[0] / NN, cmy = cmacc[1] / NN, cmz = cmacc[2] / NN;

    if (tid < HH) {
        int h = tid;
        float nx = y_pred[(b * HH + h) * 4 + 0];
        float ny = y_pred[(b * HH + h) * 4 + 1];
        float nz = y_pred[(b * HH + h) * 4 + 2];
        float d  = y_pred[(b * HH + h) * 4 + 3];
        float inv = 1.0f / sqrtf(nx * nx + ny * ny + nz * nz);
        nx *= inv; ny *= inv; nz *= inv;
        nx_s[h] = nx; ny_s[h] = ny; nz_s[h] = nz; d_s[h] = d;
        // both chamfer terms equal -> 2/N * per-bh sum
        sde_s[h] = ws[SUMBASE + b * HH + h] * (2.0f / NN);
    }
    __syncthreads();

    if (tid < HH) {
        int h = tid;
        float mn = sde_s[0], mx = sde_s[0];
        for (int g = 1; g < HH; ++g) {
            mn = fminf(mn, sde_s[g]);
            mx = fmaxf(mx, sde_s[g]);
        }
        float sde  = sde_s[h];
        float conf = 1.0f - (sde - mn) / fabsf(mx - mn);
        conf_s[h]  = conf;
        bool valid = (sde <= 10.0f);
        bool sup   = false;
        if (valid) {
            for (int g = 0; g < HH; ++g) {
                if (g == h) continue;
                float c = nx_s[h] * nx_s[g] + ny_s[h] * ny_s[g] + nz_s[h] * nz_s[g];
                c = fminf(1.0f, fmaxf(-1.0f, c));
                float ang = acosf(c) * 57.29577951308232f;
                bool close = (ang < 30.0f) || (180.0f - ang < 30.0f);
                if (close && (sde_s[g] <= 10.0f) && (sde >= sde_s[g])) sup = true;
            }
        }
        keep_s[h] = (valid && !sup) ? 1 : 0;
    }
    __syncthreads();

    if (tid < HH) {
        int h = tid;
        // stable descending rank on key = keep ? conf : -inf (jnp.argsort(-key))
        float keyh = keep_s[h] ? conf_s[h] : -INFINITY;
        int pos = 0;
        for (int g = 0; g < HH; ++g) {
            float keyg = keep_s[g] ? conf_s[g] : -INFINITY;
            if (keyg > keyh || (keyg == keyh && g < h)) ++pos;
        }
        float nx = nx_s[h], ny = ny_s[h], nz = nz_s[h];
        float t  = nx * cmx + ny * cmy + nz * cmz + d_s[h];
        float px = cmx - t * nx, py = cmy - t * ny, pz = cmz - t * nz;

        float* o = out + (size_t)(b * HH + pos) * 8;
        if (keep_s[h]) {
            o[0] = nx; o[1] = ny; o[2] = nz;
            o[3] = px; o[4] = py; o[5] = pz;
            o[6] = conf_s[h];
            o[7] = sde_s[h];
        } else {
            for (int c = 0; c < 8; ++c) o[c] = 0.0f;
        }
    }
}

extern "C" void kernel_launch(void* const* d_in, const int* in_sizes, int n_in,
                              void* d_out, int out_size, void* d_ws, size_t ws_size,
                              hipStream_t stream) {
    const float* y_pred = (const float*)d_in[0];   // (8,16,4) f32
    const float* sp     = (const float*)d_in[1];   // (8,1024,3) f32
    float* out          = (float*)d_out;           // (8,16,8) f32
    float* ws           = (float*)d_ws;            // 2 MB partials + 128 sums

    chamfer_kernel<<<dim3(BB * HH * NSC), dim3(TB), 0, stream>>>(y_pred, sp, ws);
    reduce_kernel<<<dim3(BB * HH), dim3(TB), 0, stream>>>(ws, ws);
    finalize_kernel<<<dim3(BB), dim3(TB), 0, stream>>>(ws, y_pred, sp, out);
}